// Round 7
// baseline (78.841 us; speedup 1.0000x reference)
//
#include <hip/hip_runtime.h>
#include <math.h>

#define NSLC 2
#define NPC 3
#define ETL 4
#define NCHA 4
#define NX 128
#define NY 128
#define NLIN 128
#define NCOL 256
#define NLIN_PE 32            // lines per echo
#define NB 8                  // nslc*ncha
#define NTILE 64              // 16-row tiles per echo

typedef __attribute__((ext_vector_type(8))) short short8;
typedef __attribute__((ext_vector_type(4))) float float4_t;

#define AS1 __attribute__((address_space(1)))
#define AS3 __attribute__((address_space(3)))

static __device__ __forceinline__ unsigned short f2bf(float f) {
  unsigned u = __float_as_uint(f);
  unsigned r = (u + 0x7FFFu + ((u >> 16) & 1u)) >> 16;
  return (unsigned short)r;
}

// ---------------------------------------------------------------------------
// A layout (bf16 elements): addr = (e*64 + rt)*4096 + g*128 + r*8 + j
//   row = rt*16 + r   (row = b*NX + x  ->  rt = b*8 + (x>>4), r = x&15)
//   k   = g*8 + j     (k<128: Re(coil) at y=k ; k>=128: Im at y=k-128)
// UNCHANGED from the verified R3 kernel.
// ---------------------------------------------------------------------------
__global__ __launch_bounds__(256) void prep_coil(
    const float* __restrict__ imR, const float* __restrict__ imI,
    const float* __restrict__ smR, const float* __restrict__ smI,
    const float* __restrict__ Dm, unsigned short* __restrict__ A) {
  int tid = blockIdx.x * blockDim.x + threadIdx.x;  // (s, x, y)
  if (tid >= NSLC * NX * NY) return;
  int y = tid & (NY - 1);
  int x = (tid >> 7) & (NX - 1);
  int s = tid >> 14;

  float ir[NPC], ii[NPC];
#pragma unroll
  for (int p = 0; p < NPC; ++p) {
    int idx = ((s * NPC + p) * NX + x) * NY + y;
    ir[p] = imR[idx];
    ii[p] = imI[idx];
  }
  float sr[NCHA], si[NCHA];
#pragma unroll
  for (int c = 0; c < NCHA; ++c) {
    int idx = ((s * NCHA + c) * NX + x) * NY + y;
    sr[c] = smR[idx];
    si[c] = smI[idx];
  }
#pragma unroll
  for (int e = 0; e < ETL; ++e) {
    float gr = 0.f, gi = 0.f;
#pragma unroll
    for (int p = 0; p < NPC; ++p) {
      float d = Dm[(s * ETL + e) * NPC + p];
      gr += d * ir[p];
      gi += d * ii[p];
    }
#pragma unroll
    for (int c = 0; c < NCHA; ++c) {
      int row = (s * NCHA + c) * NX + x;
      int rt = row >> 4;
      float cr = gr * sr[c] - gi * si[c];
      float ci = gr * si[c] + gi * sr[c];
      unsigned short* dst = A + (e * NTILE + rt) * 4096 + (row & 15) * 8 + (y & 7);
      dst[(y >> 3) * 128] = f2bf(cr);
      dst[(16 + (y >> 3)) * 128] = f2bf(ci);
    }
  }
}

// ---------------------------------------------------------------------------
// Main: block = (echo, 32 m-points), 4 waves. Wave w owns tiles
// rt = w*16 + i (contiguous) => coil images b in {2w, 2w+1}, ALL 32 m.
// R3-verbatim private staging: per-wave 2x8KB double buffer, lgkmcnt(0) WAR
// guard, counted vmcnt(8). B (32 m, full K) and ex factors in registers.
// NO barriers, NO cross-wave communication anywhere.
// ---------------------------------------------------------------------------
__global__ __launch_bounds__(256, 1) void radtse_mfma(
    const unsigned short* __restrict__ A, const float* __restrict__ traj,
    const float* __restrict__ mask, float* __restrict__ out) {
  __shared__ __align__(16) char lds[65536];  // 4 waves x 2 x 8 KB private

  const int tid = threadIdx.x;
  const int w = tid >> 6;
  const int lane = tid & 63;
  const int e = blockIdx.x >> 8;
  const int m0 = (blockIdx.x & 255) << 5;   // 32 m per block
  const int lin = e * NLIN_PE + (m0 >> 8);  // shared by all 32 m
  const int mloc = lane & 15;
  const int ksl = lane >> 4;  // k-slice (A/B) and D-row group

  // ---- trajectory for my two m-columns ----
  float kyv[2], kxv[2];
#pragma unroll
  for (int mg = 0; mg < 2; ++mg) {
    const int col = (m0 + mg * 16 + mloc) & (NCOL - 1);
    kxv[mg] = traj[(lin * NCOL + col) * 2 + 0];
    kyv[mg] = traj[(lin * NCOL + col) * 2 + 1];
  }

  // ---- B fragments in registers: bfr[mg][ri][kk], k = kk*32 + ksl*8 + j ----
  short8 bfr[2][2][8];
#pragma unroll
  for (int mg = 0; mg < 2; ++mg) {
#pragma unroll
    for (int kk = 0; kk < 8; ++kk) {
      short8 vr, vi;
#pragma unroll
      for (int j = 0; j < 8; ++j) {
        const int k = kk * 32 + ksl * 8 + j;
        float sn, cs;
        __sincosf(kyv[mg] * (float)((k & 127) - 64), &sn, &cs);
        vr[j] = (short)f2bf(k < 128 ? cs : sn);   // Tr col: [cos ; +sin]
        vi[j] = (short)f2bf(k < 128 ? -sn : cs);  // Ti col: [-sin ; cos]
      }
      bfr[mg][0][kk] = vr;
      bfr[mg][1][kk] = vi;
    }
  }

  // ---- ex phase factors: x = band*16 + ksl*4 + r, band = i&7 ----
  float exr[2][4], exi[2][4], str[2], sti[2];
#pragma unroll
  for (int mg = 0; mg < 2; ++mg) {
#pragma unroll
    for (int r = 0; r < 4; ++r) {
      float sn, cs;
      __sincosf(kxv[mg] * (float)(ksl * 4 + r - 64), &sn, &cs);
      exr[mg][r] = cs;
      exi[mg][r] = -sn;
    }
    float sn, cs;
    __sincosf(kxv[mg] * 16.0f, &sn, &cs);
    str[mg] = cs;
    sti[mg] = -sn;
  }

  float kr[2][2], ki[2][2];  // [mg][bl], b = 2w + bl
#pragma unroll
  for (int mg = 0; mg < 2; ++mg)
#pragma unroll
    for (int bl = 0; bl < 2; ++bl) {
      kr[mg][bl] = 0.f;
      ki[mg][bl] = 0.f;
    }

  const char* Ae = (const char*)(A + e * (NTILE * 4096));
  char* mybuf = lds + w * 16384;  // my two private 8 KB buffers

  // Stage tile i (rt = w*16 + i) into my private buffer (i&1). LDS base
  // wave-uniform (hardware adds lane*16); global source per-lane.
  auto STAGE = [&](int i) {
    const char* src = Ae + (w * 16 + i) * 8192 + lane * 16;
    char* d = mybuf + (i & 1) * 8192;
#pragma unroll
    for (int j = 0; j < 8; ++j)
      __builtin_amdgcn_global_load_lds((const AS1 unsigned int*)(src + j * 1024),
                                       (AS3 unsigned int*)(d + j * 1024), 16, 0,
                                       0);
  };

  STAGE(0);

#pragma unroll
  for (int i = 0; i < 16; ++i) {
    const int bl = i >> 3;  // static under full unroll
    // WAR: my ds_reads of buffer ((i+1)&1) [tile i-1] done before overwrite
    asm volatile("s_waitcnt lgkmcnt(0)" ::: "memory");
    if (i < 15) {
      STAGE(i + 1);
      asm volatile("s_waitcnt vmcnt(8)" ::: "memory");  // tile i landed
    } else {
      asm volatile("s_waitcnt vmcnt(0)" ::: "memory");
    }

    const char* ab = mybuf + (i & 1) * 8192 + ksl * 256 + mloc * 16;
    short8 afr[8];
#pragma unroll
    for (int kk = 0; kk < 8; ++kk)
      afr[kk] = *(const short8*)(ab + kk * 1024);

#pragma unroll
    for (int mg = 0; mg < 2; ++mg) {
      float4_t aR = {0.f, 0.f, 0.f, 0.f};
      float4_t aI = {0.f, 0.f, 0.f, 0.f};
#pragma unroll
      for (int kk = 0; kk < 8; ++kk) {
        aR = __builtin_amdgcn_mfma_f32_16x16x32_bf16(afr[kk], bfr[mg][0][kk],
                                                     aR, 0, 0, 0);
        aI = __builtin_amdgcn_mfma_f32_16x16x32_bf16(afr[kk], bfr[mg][1][kk],
                                                     aI, 0, 0, 0);
      }
      // fold: x = (i&7)*16 + ksl*4 + r, D row = ksl*4 + r, D col = mloc
#pragma unroll
      for (int r = 0; r < 4; ++r) {
        kr[mg][bl] += aR[r] * exr[mg][r] - aI[r] * exi[mg][r];
        ki[mg][bl] += aR[r] * exi[mg][r] + aI[r] * exr[mg][r];
      }
    }

    if (i == 7) {
      // reset ex to band 0 for the second b (tiles i=8..15)
#pragma unroll
      for (int mg = 0; mg < 2; ++mg)
#pragma unroll
        for (int r = 0; r < 4; ++r) {
          float sn, cs;
          __sincosf(kxv[mg] * (float)(ksl * 4 + r - 64), &sn, &cs);
          exr[mg][r] = cs;
          exi[mg][r] = -sn;
        }
    } else if (i < 15) {
      // advance ex by e^{-i*16*kx}
#pragma unroll
      for (int mg = 0; mg < 2; ++mg)
#pragma unroll
        for (int r = 0; r < 4; ++r) {
          float nr = exr[mg][r] * str[mg] - exi[mg][r] * sti[mg];
          exi[mg][r] = exr[mg][r] * sti[mg] + exi[mg][r] * str[mg];
          exr[mg][r] = nr;
        }
    }
  }

  // ---- reduce over D-row groups (xor 16/32 preserves mloc) ----
#pragma unroll
  for (int mg = 0; mg < 2; ++mg)
#pragma unroll
    for (int bl = 0; bl < 2; ++bl) {
      kr[mg][bl] += __shfl_xor(kr[mg][bl], 16, 64);
      kr[mg][bl] += __shfl_xor(kr[mg][bl], 32, 64);
      ki[mg][bl] += __shfl_xor(ki[mg][bl], 16, 64);
      ki[mg][bl] += __shfl_xor(ki[mg][bl], 32, 64);
    }

  // ---- direct store: wave w owns b = 2w+bl completely, all 32 m ----
  if (lane < 16) {
#pragma unroll
    for (int mg = 0; mg < 2; ++mg) {
      const int col = (m0 + mg * 16 + lane) & (NCOL - 1);
#pragma unroll
      for (int bl = 0; bl < 2; ++bl) {
        const int b = 2 * w + bl;
        const int s = b >> 2;
        const float mv = mask[(s * NLIN + lin) * NCOL + col];
        float2 o = make_float2(kr[mg][bl] * mv, ki[mg][bl] * mv);
        *(float2*)(out + (((b * NLIN) + lin) * NCOL + col) * 2) = o;
      }
    }
  }
}

extern "C" void kernel_launch(void* const* d_in, const int* in_sizes, int n_in,
                              void* d_out, int out_size, void* d_ws, size_t ws_size,
                              hipStream_t stream) {
  const float* imR = (const float*)d_in[0];
  const float* imI = (const float*)d_in[1];
  const float* smR = (const float*)d_in[2];
  const float* smI = (const float*)d_in[3];
  const float* Dm = (const float*)d_in[4];
  const float* mask = (const float*)d_in[5];
  const float* traj = (const float*)d_in[6];
  float* out = (float*)d_out;
  unsigned short* A = (unsigned short*)d_ws;  // 2 MB: [ETL][64 tiles][4096]

  prep_coil<<<dim3(NSLC * NX * NY / 256), dim3(256), 0, stream>>>(imR, imI, smR,
                                                                  smI, Dm, A);
  radtse_mfma<<<dim3(ETL * 256), dim3(256), 0, stream>>>(A, traj, mask, out);
}